// Round 9
// baseline (440.172 us; speedup 1.0000x reference)
//
#include <hip/hip_runtime.h>
#include <hip/hip_bf16.h>

// LengthRegulator: out[b,t,:] = x[b, searchsorted_right(cum[b], t).clip(0,L-1), :]
//                  masked to 0 where t >= cum[b, L-1].
// B=32, L=1024, D=384, MAX_LEN=8192. fp32 in/out.
// Timed region ≈ 2.52 GB irreducible HBM traffic (1.61 GB ws poison + 403 MB
// out poison + ~130 MB restore + our 403 MB write + ~50 MB read) => floor
// ~409 us at 6.3 TB/s. R8 best = 436.7 us (+7%).
//
// History: R5 fused scan +23; R6 (no-LDS + 8-deep + XCD swizzle) +120;
// R7 persistent +45; R8 shfl-scan -2.6.
// R9 = R8 + ONE change: kernel B idx staging LDS+barrier -> hoisted
// per-thread broadcast loads (R6 minus swizzle). Tests whether R6's
// regression was the swizzle (predicted) or the no-LDS form.

#define B_FIXED 32
#define L_FIXED 1024
#define ROW_F4 96        // 384 floats / 4
#define RPB 32           // output rows per copy block

typedef float vfloat4 __attribute__((ext_vector_type(4)));

// Kernel A: per-batch inclusive scan of round(clip(dur,0)) (shfl wave-scan,
// 3 barriers), then searchsorted_right for all t. idx = -1 where masked.
__global__ __launch_bounds__(1024) void lr_scan_idx_kernel(
    const float* __restrict__ durations, int* __restrict__ idx, int max_len) {
    __shared__ int s[L_FIXED];
    __shared__ int wsum[16];
    const int b = blockIdx.x;
    const int tid = threadIdx.x;
    const int lane = tid & 63;
    const int wid = tid >> 6;          // 16 waves

    int v = (int)rintf(fmaxf(durations[b * L_FIXED + tid], 0.0f));

    int sc = v;
#pragma unroll
    for (int off = 1; off < 64; off <<= 1) {
        int n = __shfl_up(sc, off, 64);
        if (lane >= off) sc += n;
    }
    if (lane == 63) wsum[wid] = sc;
    __syncthreads();

    if (tid < 16) {
        int w = wsum[tid];
#pragma unroll
        for (int off = 1; off < 16; off <<= 1) {
            int n = __shfl_up(w, off, 64);
            if (tid >= off) w += n;
        }
        wsum[tid] = w;
    }
    __syncthreads();

    s[tid] = sc + ((wid > 0) ? wsum[wid - 1] : 0);
    __syncthreads();

    const int total = s[L_FIXED - 1];
    for (int t = tid; t < max_len; t += 1024) {
        int lo = 0, hi = L_FIXED;
        while (lo < hi) {
            int mid = (lo + hi) >> 1;
            if (s[mid] <= t) lo = mid + 1; else hi = mid;
        }
        int r = min(lo, L_FIXED - 1);
        idx[b * max_len + t] = (t < total) ? r : -1;
    }
}

// Kernel B: streaming gather-copy. Block (96,4), linear tile order.
// idx via hoisted per-thread broadcast loads (no LDS, no barrier);
// 2-deep gather/store pattern; nontemporal stores.
__global__ __launch_bounds__(384) void lr_copy_kernel(
    const vfloat4* __restrict__ x, const int* __restrict__ idx,
    vfloat4* __restrict__ out, int max_len) {
    const int b = blockIdx.y;
    const int t0 = blockIdx.x * RPB;
    const int cx = threadIdx.x;
    const int y  = threadIdx.y;
    const long xbase = (long)b * L_FIXED * ROW_F4;
    const long obase = ((long)b * max_len + t0) * ROW_F4;
    const vfloat4 zero = {0.f, 0.f, 0.f, 0.f};
    const int* idx_p = idx + b * max_len + t0 + y;

    int row[8];                        // rows y + 4j, j=0..7
#pragma unroll
    for (int j = 0; j < 8; ++j) row[j] = idx_p[4 * j];   // wave-broadcast

#pragma unroll
    for (int k = 0; k < 4; ++k) {
        const int ra = y + 8 * k;
        const int rb = ra + 4;
        const int rowa = row[2 * k];
        const int rowb = row[2 * k + 1];
        vfloat4 va = zero, vb = zero;
        if (rowa >= 0) va = x[xbase + (long)rowa * ROW_F4 + cx];
        if (rowb >= 0) vb = x[xbase + (long)rowb * ROW_F4 + cx];
        __builtin_nontemporal_store(va, &out[obase + (long)ra * ROW_F4 + cx]);
        __builtin_nontemporal_store(vb, &out[obase + (long)rb * ROW_F4 + cx]);
    }
}

extern "C" void kernel_launch(void* const* d_in, const int* in_sizes, int n_in,
                              void* d_out, int out_size, void* d_ws, size_t ws_size,
                              hipStream_t stream) {
    const float* x = (const float*)d_in[0];          // (B, L, D) fp32
    const float* durations = (const float*)d_in[1];  // (B, L) fp32
    const int MAX_LEN = 8192;

    int* idx = (int*)d_ws;  // B * MAX_LEN ints = 1 MB scratch

    lr_scan_idx_kernel<<<B_FIXED, 1024, 0, stream>>>(durations, idx, MAX_LEN);

    dim3 grid(MAX_LEN / RPB, B_FIXED);               // (256, 32)
    dim3 block(96, 4);
    lr_copy_kernel<<<grid, block, 0, stream>>>(
        (const vfloat4*)x, idx, (vfloat4*)d_out, MAX_LEN);
}